// Round 13
// baseline (79.813 us; speedup 1.0000x reference)
//
#include <hip/hip_runtime.h>

namespace {
constexpr int HIN = 130, WIN = 130;
constexpr int HH = 128, WW = 128;
constexpr int C = 128, CR = 32, B = 8;
constexpr int CHW = HIN * WIN;   // 16900

// Transpose W_reduce (32x128) -> WredT (128x32): the unrolled r-loop then
// reads contiguous uniform floats (compiler scalarizes to s_load_dwordx*).
__global__ void transpose_wred(const float* __restrict__ Wred, float* __restrict__ WredT) {
    int idx = blockIdx.x * 256 + threadIdx.x;   // 4096 elements
    int r = idx >> 7;
    int c = idx & 127;
    WredT[c * CR + r] = Wred[r * C + c];
}

// lgkm-only workgroup barrier: leaves global loads (vmcnt) in flight.
__device__ __forceinline__ void lgkm_barrier() {
    asm volatile("s_waitcnt lgkmcnt(0)\n\ts_barrier" ::: "memory");
    __builtin_amdgcn_sched_barrier(0);
}

// ---- stage-3 pipeline macros: named float2 registers, no arrays/lambdas ----
// (R11/R12 lesson: array buffers passed through lambdas + launch_bounds(256,4)
//  => allocator pinned VGPR=64 and put buffers in scratch, WRITE_SIZE 65->94/207 MB)
#define DECLBUF(T) float2 T##0, T##1, T##2, T##3, T##4, T##5, \
                          T##6, T##7, T##8, T##9, T##10, T##11

// chunk j = channels 32q+2j, 32q+2j+1; rows h..h+2, col pairs {2p, 2p+2}
#define LDC(T, j) do { \
    const float* xp_ = xrow + (size_t)(32 * q + 2 * (j)) * CHW; \
    T##0 = *(const float2*)(xp_);            T##1 = *(const float2*)(xp_ + 2); \
    T##2 = *(const float2*)(xp_ + WIN);      T##3 = *(const float2*)(xp_ + WIN + 2); \
    T##4 = *(const float2*)(xp_ + 2 * WIN);  T##5 = *(const float2*)(xp_ + 2 * WIN + 2); \
    const float* xq_ = xp_ + CHW; \
    T##6 = *(const float2*)(xq_);            T##7 = *(const float2*)(xq_ + 2); \
    T##8 = *(const float2*)(xq_ + WIN);      T##9 = *(const float2*)(xq_ + WIN + 2); \
    T##10 = *(const float2*)(xq_ + 2 * WIN); T##11 = *(const float2*)(xq_ + 2 * WIN + 2); \
} while (0)

// pixel0 taps row i: L.x L.y R.x ; pixel1: L.y R.x R.y
#define FMAC1(T, A, B, o0, o1, o2, o3, o4, o5, joff) do { \
    float a0_ = 0.f, a1_ = 0.f; \
    a0_ = fmaf(A[0], T##o0.x, a0_); a0_ = fmaf(A[1], T##o0.y, a0_); a0_ = fmaf(A[2], T##o1.x, a0_); \
    a1_ = fmaf(B[0], T##o0.y, a1_); a1_ = fmaf(B[1], T##o1.x, a1_); a1_ = fmaf(B[2], T##o1.y, a1_); \
    a0_ = fmaf(A[3], T##o2.x, a0_); a0_ = fmaf(A[4], T##o2.y, a0_); a0_ = fmaf(A[5], T##o3.x, a0_); \
    a1_ = fmaf(B[3], T##o2.y, a1_); a1_ = fmaf(B[4], T##o3.x, a1_); a1_ = fmaf(B[5], T##o3.y, a1_); \
    a0_ = fmaf(A[6], T##o4.x, a0_); a0_ = fmaf(A[7], T##o4.y, a0_); a0_ = fmaf(A[8], T##o5.x, a0_); \
    a1_ = fmaf(B[6], T##o4.y, a1_); a1_ = fmaf(B[7], T##o5.x, a1_); a1_ = fmaf(B[8], T##o5.y, a1_); \
    *(float2*)(op + (size_t)(joff) * HH * WW) = make_float2(a0_, a1_); \
} while (0)

#define FMAC(T, j) do { \
    FMAC1(T, khA, khB, 0, 1, 2, 3, 4, 5, 2 * (j)); \
    FMAC1(T, khA, khB, 6, 7, 8, 9, 10, 11, 2 * (j) + 1); \
} while (0)

#define KERNHALF(half) do { \
    _Pragma("unroll") \
    for (int k = 0; k < 9; ++k) { khA[k] = bkern[18 * q + 9 * (half) + k]; khB[k] = khA[k]; } \
    _Pragma("unroll") \
    for (int r = 0; r < CR; ++r) { \
        float2 rv_ = *(const float2*)&red2[r][2 * p]; \
        _Pragma("unroll") \
        for (int k = 0; k < 9; ++k) { \
            float wgt_ = Wkern[(18 * q + 9 * (half) + k) * CR + r]; \
            khA[k] = fmaf(wgt_, rv_.x, khA[k]); \
            khB[k] = fmaf(wgt_, rv_.y, khB[k]); \
        } \
    } \
} while (0)

// Block = 256 threads = 4 waves x 64 lanes; one full output row, 2 adjacent
// pixels per thread. Wave q owns groups {2q,2q+1}, channels [32q,32q+32).
// Plain launch_bounds(256): grid is 4 blocks/CU anyway, and <=128 VGPR keeps
// 4 waves/SIMD, so letting the allocator float (R8: 116 regs, no spill) is free.
__global__ __launch_bounds__(256) void invol_direct(
    const float* __restrict__ x,      // [B][C][130][130]
    const float* __restrict__ WredT,  // [128][32]
    const float* __restrict__ bred,   // [32]
    const float* __restrict__ Wkern,  // [72][32]
    const float* __restrict__ bkern,  // [72]
    float* __restrict__ out)          // [B][C][128][128]
{
    __shared__ float red2[CR][128];   // [r][pixel], b64 access, 16 KB

    const int t = threadIdx.x;
    const int p = t & 63;
    const int q = __builtin_amdgcn_readfirstlane(t >> 6);

    // XCD-chunked swizzle: h-adjacent blocks (sharing 2/3 tap rows) land on
    // the same XCD L2. 1024 % 8 == 0 -> bijective.
    const int orig = blockIdx.x;
    const int blk  = (orig & 7) * 128 + (orig >> 3);
    const int b    = blk >> 7;
    const int h    = blk & (HH - 1);

    const float* xb = x + (size_t)b * C * CHW;

    // ======== stage 1: red[8q..8q+8) for pixels 2p,2p+1 (R10 form) =======
    const float* xc = xb + (size_t)(h + 1) * WIN + (2 * p + 1);
    float r0[8], r1[8];
#pragma unroll
    for (int r = 0; r < 8; ++r) { r0[r] = bred[q * 8 + r]; r1[r] = r0[r]; }

#pragma unroll
    for (int cb = 0; cb < 4; ++cb) {
        float xv0[32], xv1[32];
#pragma unroll
        for (int cc = 0; cc < 32; ++cc) {
            const float* cp = xc + (size_t)(cb * 32 + cc) * CHW;
            xv0[cc] = cp[0];
            xv1[cc] = cp[1];
        }
#pragma unroll
        for (int cc = 0; cc < 32; ++cc) {
#pragma unroll
            for (int r = 0; r < 8; ++r) {
                float wgt = WredT[(cb * 32 + cc) * CR + q * 8 + r];   // uniform
                r0[r] = fmaf(wgt, xv0[cc], r0[r]);
                r1[r] = fmaf(wgt, xv1[cc], r1[r]);
            }
        }
    }
#pragma unroll
    for (int r = 0; r < 8; ++r)
        *(float2*)&red2[q * 8 + r][2 * p] = make_float2(r0[r], r1[r]);

    // ======== stage 3 pipeline ==========================================
    const float* xrow = xb + (size_t)h * WIN + 2 * p;
    float* op = out + (((size_t)(b * C + 32 * q)) * HH + h) * WW + 2 * p;

    float khA[9], khB[9];
    DECLBUF(U); DECLBUF(V); DECLBUF(W);

    // chunks 0,1 in flight across the barrier, hidden under KERNHALF(0)
    LDC(U, 0); LDC(V, 1);
    lgkm_barrier();
    KERNHALF(0);

    LDC(W, 2);   FMAC(U, 0);
    LDC(U, 3);   FMAC(V, 1);
    LDC(V, 4);   FMAC(W, 2);
    LDC(W, 5);   FMAC(U, 3);
    LDC(U, 6);   FMAC(V, 4);
    LDC(V, 7);   FMAC(W, 5);
    LDC(W, 8);   FMAC(U, 6);
    LDC(U, 9);   FMAC(V, 7);
    KERNHALF(1);                 // chunks 8,9 already in flight
    LDC(V, 10);  FMAC(W, 8);
    LDC(W, 11);  FMAC(U, 9);
    LDC(U, 12);  FMAC(V, 10);
    LDC(V, 13);  FMAC(W, 11);
    LDC(W, 14);  FMAC(U, 12);
    LDC(U, 15);  FMAC(V, 13);
    FMAC(W, 14);
    FMAC(U, 15);
}
} // namespace

extern "C" void kernel_launch(void* const* d_in, const int* in_sizes, int n_in,
                              void* d_out, int out_size, void* d_ws, size_t ws_size,
                              hipStream_t stream) {
    const float* x     = (const float*)d_in[0];
    const float* Wred  = (const float*)d_in[1];
    const float* bred  = (const float*)d_in[2];
    const float* Wkern = (const float*)d_in[3];
    const float* bkern = (const float*)d_in[4];
    float* out   = (float*)d_out;
    float* WredT = (float*)d_ws;   // 16 KB scratch

    transpose_wred<<<16, 256, 0, stream>>>(Wred, WredT);

    // 8 b * 128 h = 1024 blocks, one full output row each
    invol_direct<<<1024, 256, 0, stream>>>(x, WredT, bred, Wkern, bkern, out);
}

// Round 14
// 77.507 us; speedup vs baseline: 1.0297x; 1.0297x over previous
//
#include <hip/hip_runtime.h>

namespace {
constexpr int HIN = 130, WIN = 130;
constexpr int HH = 128, WW = 128;
constexpr int C = 128, CR = 32, B = 8;
constexpr int CHW = HIN * WIN;   // 16900

// Transpose W_reduce (32x128) -> WredT (128x32): the unrolled r-loop then
// reads contiguous uniform floats (compiler scalarizes to s_load_dwordx*).
__global__ void transpose_wred(const float* __restrict__ Wred, float* __restrict__ WredT) {
    int idx = blockIdx.x * 256 + threadIdx.x;   // 4096 elements
    int r = idx >> 7;
    int c = idx & 127;
    WredT[c * CR + r] = Wred[r * C + c];
}

// lgkm-only workgroup barrier: leaves global loads (vmcnt) in flight.
__device__ __forceinline__ void lgkm_barrier() {
    asm volatile("s_waitcnt lgkmcnt(0)\n\ts_barrier" ::: "memory");
    __builtin_amdgcn_sched_barrier(0);
}

// Block = 256 threads = 4 waves x 64 lanes; one full output row, 2 adjacent
// pixels per thread. Wave q owns groups {2q,2q+1}, channels [32q,32q+32).
// R14 = R10 base (best: 58.6us) + two edits aimed at one mechanism
// (stage-1 load/compute overlap):
//   (a) plain launch_bounds(256): grid caps residency at 4 blocks/CU anyway;
//       <=128 VGPR keeps 4 waves/SIMD, so lifting the 64-reg cap is free.
//   (b) stage-1 chunks of 16 channels (32 regs/buffer): at ~100 VGPR the
//       scheduler can hoist chunk k+1's 32 loads into chunk k's 256 FMAs.
// R11-R13 lesson: manual straight-line pipelines all lost to the compiler's
// own scheduling of compact loops — keep loops, give the scheduler room.
__global__ __launch_bounds__(256) void invol_direct(
    const float* __restrict__ x,      // [B][C][130][130]
    const float* __restrict__ WredT,  // [128][32]
    const float* __restrict__ bred,   // [32]
    const float* __restrict__ Wkern,  // [72][32]
    const float* __restrict__ bkern,  // [72]
    float* __restrict__ out)          // [B][C][128][128]
{
    __shared__ float red2[CR][128];   // [r][pixel], b64 access, 16 KB

    const int t = threadIdx.x;
    const int p = t & 63;
    const int q = __builtin_amdgcn_readfirstlane(t >> 6);

    // XCD-chunked swizzle: h-adjacent blocks (sharing 2/3 tap rows) land on
    // the same XCD L2. 1024 % 8 == 0 -> bijective.
    const int orig = blockIdx.x;
    const int blk  = (orig & 7) * 128 + (orig >> 3);
    const int b    = blk >> 7;
    const int h    = blk & (HH - 1);

    const float* xb = x + (size_t)b * C * CHW;

    // ======== stage 1: red[8q..8q+8) for pixels 2p,2p+1 =================
    const float* xc = xb + (size_t)(h + 1) * WIN + (2 * p + 1);
    float r0[8], r1[8];
#pragma unroll
    for (int r = 0; r < 8; ++r) { r0[r] = bred[q * 8 + r]; r1[r] = r0[r]; }

#pragma unroll
    for (int cb = 0; cb < 8; ++cb) {
        float xv0[16], xv1[16];
#pragma unroll
        for (int cc = 0; cc < 16; ++cc) {
            const float* cp = xc + (size_t)(cb * 16 + cc) * CHW;
            xv0[cc] = cp[0];
            xv1[cc] = cp[1];
        }
#pragma unroll
        for (int cc = 0; cc < 16; ++cc) {
#pragma unroll
            for (int r = 0; r < 8; ++r) {
                float wgt = WredT[(cb * 16 + cc) * CR + q * 8 + r];   // uniform
                r0[r] = fmaf(wgt, xv0[cc], r0[r]);
                r1[r] = fmaf(wgt, xv1[cc], r1[r]);
            }
        }
    }
#pragma unroll
    for (int r = 0; r < 8; ++r)
        *(float2*)&red2[q * 8 + r][2 * p] = make_float2(r0[r], r1[r]);

    lgkm_barrier();   // red2 visible to all waves; no vmcnt drain

    // ======== stage 2: kern[18] per pixel for groups {2q,2q+1} ==========
    float k0[18], k1[18];
#pragma unroll
    for (int k = 0; k < 18; ++k) { k0[k] = bkern[18 * q + k]; k1[k] = k0[k]; }
#pragma unroll
    for (int r = 0; r < CR; ++r) {
        float2 rv = *(const float2*)&red2[r][2 * p];
#pragma unroll
        for (int k = 0; k < 18; ++k) {
            float wgt = Wkern[(18 * q + k) * CR + r];   // uniform
            k0[k] = fmaf(wgt, rv.x, k0[k]);
            k1[k] = fmaf(wgt, rv.y, k1[k]);
        }
    }

    // ======== stage 3: 32 channels (32q..), taps direct from global =====
    // window cols 2p..2p+3 of rows h..h+2 serve both pixels
    const float* xrow = xb + (size_t)h * WIN + 2 * p;
    float* op = out + (((size_t)(b * C + 32 * q)) * HH + h) * WW + 2 * p;

#pragma unroll
    for (int half = 0; half < 2; ++half) {   // group 2q+half, static kern slice
        float kh0[9], kh1[9];
#pragma unroll
        for (int k = 0; k < 9; ++k) { kh0[k] = k0[9 * half + k]; kh1[k] = k1[9 * half + k]; }

#pragma unroll 2
        for (int cc = 0; cc < 16; ++cc) {
            const float* xp = xrow + (size_t)(32 * q + 16 * half + cc) * CHW;
            float2 ta[3], tb[3];
#pragma unroll
            for (int i = 0; i < 3; ++i) {
                ta[i] = *(const float2*)(xp + i * WIN);       // cols 2p,2p+1
                tb[i] = *(const float2*)(xp + i * WIN + 2);   // cols 2p+2,2p+3
            }
            float a0 = 0.f, a1 = 0.f;
#pragma unroll
            for (int i = 0; i < 3; ++i) {
                a0 = fmaf(kh0[3 * i + 0], ta[i].x, a0);
                a0 = fmaf(kh0[3 * i + 1], ta[i].y, a0);
                a0 = fmaf(kh0[3 * i + 2], tb[i].x, a0);
                a1 = fmaf(kh1[3 * i + 0], ta[i].y, a1);
                a1 = fmaf(kh1[3 * i + 1], tb[i].x, a1);
                a1 = fmaf(kh1[3 * i + 2], tb[i].y, a1);
            }
            *(float2*)(op + (size_t)(16 * half + cc) * HH * WW) = make_float2(a0, a1);
        }
    }
}
} // namespace

extern "C" void kernel_launch(void* const* d_in, const int* in_sizes, int n_in,
                              void* d_out, int out_size, void* d_ws, size_t ws_size,
                              hipStream_t stream) {
    const float* x     = (const float*)d_in[0];
    const float* Wred  = (const float*)d_in[1];
    const float* bred  = (const float*)d_in[2];
    const float* Wkern = (const float*)d_in[3];
    const float* bkern = (const float*)d_in[4];
    float* out   = (float*)d_out;
    float* WredT = (float*)d_ws;   // 16 KB scratch

    transpose_wred<<<16, 256, 0, stream>>>(Wred, WredT);

    // 8 b * 128 h = 1024 blocks, one full output row each
    invol_direct<<<1024, 256, 0, stream>>>(x, WredT, bred, Wkern, bkern, out);
}

// Round 15
// 62.054 us; speedup vs baseline: 1.2862x; 1.2490x over previous
//
#include <hip/hip_runtime.h>

namespace {
constexpr int HIN = 130, WIN = 130;
constexpr int HH = 128, WW = 128;
constexpr int C = 128, CR = 32, B = 8;
constexpr int CHW = HIN * WIN;   // 16900

// Transpose W_reduce (32x128) -> WredT (128x32): the unrolled r-loop then
// reads contiguous uniform floats (compiler scalarizes to s_load_dwordx*).
__global__ void transpose_wred(const float* __restrict__ Wred, float* __restrict__ WredT) {
    int idx = blockIdx.x * 256 + threadIdx.x;   // 4096 elements
    int r = idx >> 7;
    int c = idx & 127;
    WredT[c * CR + r] = Wred[r * C + c];
}

// lgkm-only workgroup barrier: leaves global loads (vmcnt) in flight.
__device__ __forceinline__ void lgkm_barrier() {
    asm volatile("s_waitcnt lgkmcnt(0)\n\ts_barrier" ::: "memory");
    __builtin_amdgcn_sched_barrier(0);
}

// Block = 256 threads = 4 waves x 64 lanes; one full output row, 2 adjacent
// pixels per thread. Wave q owns groups {2q,2q+1}, channels [32q,32q+32).
//
// R15 = R10 base (best: 58.6us) with ONE structural change: stage-1 center
// loads were 4x-redundant scalar loads (each wave loaded all 128 channels'
// centers itself; misaligned col -> no float2 possible). Now 256 threads
// cooperatively stage each 32-channel chunk into LDS (16 coalesced dword
// loads/thread, zero redundancy), and each thread reads its pixel pair as
// ALIGNED ds_read_b64 (cs[ch][col-1] makes the pair even-indexed).
// Stage 2 / stage 3 / swizzle / grid are R10-verbatim.
__global__ __launch_bounds__(256, 4) void invol_direct(
    const float* __restrict__ x,      // [B][C][130][130]
    const float* __restrict__ WredT,  // [128][32]
    const float* __restrict__ bred,   // [32]
    const float* __restrict__ Wkern,  // [72][32]
    const float* __restrict__ bkern,  // [72]
    float* __restrict__ out)          // [B][C][128][128]
{
    __shared__ float cs[32][128];     // staged centers, one 32-ch chunk, 16 KB
    __shared__ float red2[CR][128];   // [r][pixel], b64 access, 16 KB

    const int t = threadIdx.x;
    const int p = t & 63;
    const int q = __builtin_amdgcn_readfirstlane(t >> 6);

    // XCD-chunked swizzle: h-adjacent blocks (sharing 2/3 tap rows) land on
    // the same XCD L2. 1024 % 8 == 0 -> bijective.
    const int orig = blockIdx.x;
    const int blk  = (orig & 7) * 128 + (orig >> 3);
    const int b    = blk >> 7;
    const int h    = blk & (HH - 1);

    const float* xb = x + (size_t)b * C * CHW;

    // ======== stage 1: red[8q..8q+8) for pixels 2p,2p+1 =================
    // Cooperative staging: thread t covers channel-offset (t>>7) in {0,1}
    // and column (t&127) of the center row (input row h+1, cols 1..128).
    const float* cbase = xb + (size_t)(h + 1) * WIN + 1;
    const int ch_off = t >> 7;      // wave-uniform (q>>1)
    const int col    = t & 127;

    float r0[8], r1[8];
#pragma unroll
    for (int r = 0; r < 8; ++r) { r0[r] = bred[q * 8 + r]; r1[r] = r0[r]; }

    float st[16];
    // load chunk 0 (channels 0..31): 16 coalesced dwords/thread
#pragma unroll
    for (int j = 0; j < 16; ++j)
        st[j] = cbase[(size_t)(2 * j + ch_off) * CHW + col];
    // write chunk 0 (compiler inserts vmcnt waits on st[])
#pragma unroll
    for (int j = 0; j < 16; ++j)
        cs[2 * j + ch_off][col] = st[j];
    lgkm_barrier();   // chunk-0 writes visible

#pragma unroll
    for (int k = 0; k < 4; ++k) {
        // prefetch chunk k+1 (in flight during this chunk's 512 FMAs)
        if (k < 3) {
#pragma unroll
            for (int j = 0; j < 16; ++j)
                st[j] = cbase[(size_t)(32 * (k + 1) + 2 * j + ch_off) * CHW + col];
        }
        // consume chunk k: aligned b64 center-pair reads from LDS
#pragma unroll
        for (int cc = 0; cc < 32; ++cc) {
            float2 xv = *(const float2*)&cs[cc][2 * p];
#pragma unroll
            for (int r = 0; r < 8; ++r) {
                float wgt = WredT[(32 * k + cc) * CR + q * 8 + r];   // uniform
                r0[r] = fmaf(wgt, xv.x, r0[r]);
                r1[r] = fmaf(wgt, xv.y, r1[r]);
            }
        }
        if (k < 3) {
            lgkm_barrier();   // all waves done READING cs
#pragma unroll
            for (int j = 0; j < 16; ++j)
                cs[2 * j + ch_off][col] = st[j];
            lgkm_barrier();   // writes visible
        }
    }

#pragma unroll
    for (int r = 0; r < 8; ++r)
        *(float2*)&red2[q * 8 + r][2 * p] = make_float2(r0[r], r1[r]);

    lgkm_barrier();   // red2 visible to all waves

    // ======== stage 2: kern[18] per pixel for groups {2q,2q+1} ==========
    float k0[18], k1[18];
#pragma unroll
    for (int k = 0; k < 18; ++k) { k0[k] = bkern[18 * q + k]; k1[k] = k0[k]; }
#pragma unroll
    for (int r = 0; r < CR; ++r) {
        float2 rv = *(const float2*)&red2[r][2 * p];
#pragma unroll
        for (int k = 0; k < 18; ++k) {
            float wgt = Wkern[(18 * q + k) * CR + r];   // uniform
            k0[k] = fmaf(wgt, rv.x, k0[k]);
            k1[k] = fmaf(wgt, rv.y, k1[k]);
        }
    }

    // ======== stage 3: 32 channels (32q..), taps direct from global =====
    // window cols 2p..2p+3 of rows h..h+2 serve both pixels
    const float* xrow = xb + (size_t)h * WIN + 2 * p;
    float* op = out + (((size_t)(b * C + 32 * q)) * HH + h) * WW + 2 * p;

#pragma unroll
    for (int half = 0; half < 2; ++half) {   // group 2q+half, static kern slice
        float kh0[9], kh1[9];
#pragma unroll
        for (int k = 0; k < 9; ++k) { kh0[k] = k0[9 * half + k]; kh1[k] = k1[9 * half + k]; }

#pragma unroll 2
        for (int cc = 0; cc < 16; ++cc) {
            const float* xp = xrow + (size_t)(32 * q + 16 * half + cc) * CHW;
            float2 ta[3], tb[3];
#pragma unroll
            for (int i = 0; i < 3; ++i) {
                ta[i] = *(const float2*)(xp + i * WIN);       // cols 2p,2p+1
                tb[i] = *(const float2*)(xp + i * WIN + 2);   // cols 2p+2,2p+3
            }
            float a0 = 0.f, a1 = 0.f;
#pragma unroll
            for (int i = 0; i < 3; ++i) {
                a0 = fmaf(kh0[3 * i + 0], ta[i].x, a0);
                a0 = fmaf(kh0[3 * i + 1], ta[i].y, a0);
                a0 = fmaf(kh0[3 * i + 2], tb[i].x, a0);
                a1 = fmaf(kh1[3 * i + 0], ta[i].y, a1);
                a1 = fmaf(kh1[3 * i + 1], tb[i].x, a1);
                a1 = fmaf(kh1[3 * i + 2], tb[i].y, a1);
            }
            *(float2*)(op + (size_t)(16 * half + cc) * HH * WW) = make_float2(a0, a1);
        }
    }
}
} // namespace

extern "C" void kernel_launch(void* const* d_in, const int* in_sizes, int n_in,
                              void* d_out, int out_size, void* d_ws, size_t ws_size,
                              hipStream_t stream) {
    const float* x     = (const float*)d_in[0];
    const float* Wred  = (const float*)d_in[1];
    const float* bred  = (const float*)d_in[2];
    const float* Wkern = (const float*)d_in[3];
    const float* bkern = (const float*)d_in[4];
    float* out   = (float*)d_out;
    float* WredT = (float*)d_ws;   // 16 KB scratch

    transpose_wred<<<16, 256, 0, stream>>>(Wred, WredT);

    // 8 b * 128 h = 1024 blocks, one full output row each
    invol_direct<<<1024, 256, 0, stream>>>(x, WredT, bred, Wkern, bkern, out);
}

// Round 16
// 61.830 us; speedup vs baseline: 1.2908x; 1.0036x over previous
//
#include <hip/hip_runtime.h>
#include <stdint.h>

namespace {
constexpr int HIN = 130, WIN = 130;
constexpr int HH = 128, WW = 128;
constexpr int C = 128, CR = 32, B = 8;
constexpr int CHW = HIN * WIN;   // 16900

// Transpose W_reduce (32x128) -> WredT (128x32): the unrolled r-loop then
// reads contiguous uniform floats (compiler scalarizes to s_load_dwordx*).
__global__ void transpose_wred(const float* __restrict__ Wred, float* __restrict__ WredT) {
    int idx = blockIdx.x * 256 + threadIdx.x;   // 4096 elements
    int r = idx >> 7;
    int c = idx & 127;
    WredT[c * CR + r] = Wred[r * C + c];
}

// lgkm-only workgroup barrier: leaves global/DMA loads (vmcnt) in flight.
__device__ __forceinline__ void lgkm_barrier() {
    asm volatile("s_waitcnt lgkmcnt(0)\n\ts_barrier" ::: "memory");
    __builtin_amdgcn_sched_barrier(0);
}

// Counted-vmcnt barrier (T4): waits until <= N VMEM ops outstanding, then
// syncs. Never drains to 0 mid-pipeline.
template<int N>
__device__ __forceinline__ void vmcnt_barrier() {
    asm volatile("s_waitcnt vmcnt(%0)\n\ts_barrier" :: "i"(N) : "memory");
    __builtin_amdgcn_sched_barrier(0);
}

__device__ __forceinline__ void vm0lgkm_barrier() {
    asm volatile("s_waitcnt vmcnt(0) lgkmcnt(0)\n\ts_barrier" ::: "memory");
    __builtin_amdgcn_sched_barrier(0);
}

// Async global->LDS DMA, 4 B/lane (one 256 B half-row per call). Global
// address is per-lane; LDS dest is wave-uniform base + lane*4. Zero VGPRs.
__device__ __forceinline__ void stage256(const float* g, float* l) {
    __builtin_amdgcn_global_load_lds(
        (const __attribute__((address_space(1))) uint32_t*)g,
        (__attribute__((address_space(3))) uint32_t*)l, 4, 0, 0);
}

// Block = 256 threads = 4 waves x 64 lanes; one full output row, 2 adjacent
// pixels per thread. Wave q owns groups {2q,2q+1}, channels [32q,32q+32).
//
// R16 = R10 base with stage-1 centers staged via global_load_lds:
//  - R10's 256 scalar center loads/thread (4x wave-redundant, latency-bound
//    at VGPR=64) -> 16 DMA instrs/wave/chunk, zero register round-trip
//    (R15's VGPR staging spilled 12 MB; DMA can't spill).
//  - counted vmcnt(16) barriers keep the next chunk's DMA in flight across
//    the sync (T3/T4); consume = aligned ds_read_b64 + 512 FMA per chunk.
//  - red2 overlays cs[0] (dead after chunk 2) -> LDS 32 KB, 4 blocks/CU.
// Stage 2 / stage 3 / swizzle / grid are R10-verbatim.
__global__ __launch_bounds__(256, 4) void invol_direct(
    const float* __restrict__ x,      // [B][C][130][130]
    const float* __restrict__ WredT,  // [128][32]
    const float* __restrict__ bred,   // [32]
    const float* __restrict__ Wkern,  // [72][32]
    const float* __restrict__ bkern,  // [72]
    float* __restrict__ out)          // [B][C][128][128]
{
    __shared__ union SM {
        float cs[2][32][128];             // staged centers, 2 x 16 KB
        struct { float red2[32][128]; } r;  // overlays cs[0] after stage 1
    } sm;

    const int t = threadIdx.x;
    const int p = t & 63;
    const int q = __builtin_amdgcn_readfirstlane(t >> 6);

    // XCD-chunked swizzle: h-adjacent blocks (sharing 2/3 tap rows) land on
    // the same XCD L2. 1024 % 8 == 0 -> bijective.
    const int orig = blockIdx.x;
    const int blk  = (orig & 7) * 128 + (orig >> 3);
    const int b    = blk >> 7;
    const int h    = blk & (HH - 1);

    const float* xb = x + (size_t)b * C * CHW;

    // ======== stage 1: red[8q..8q+8) for pixels 2p,2p+1 =================
    // centers = input row h+1, cols 1..128; cs[ch][c] = x[ch][h+1][c+1]
    const float* cbase = xb + (size_t)(h + 1) * WIN + 1;

    float r0[8], r1[8];
#pragma unroll
    for (int r = 0; r < 8; ++r) { r0[r] = bred[q * 8 + r]; r1[r] = r0[r]; }

// wave q stages LDS rows q*8..q*8+7 of chunk k (16 DMA calls)
#define ISSUE(k, bi) do { \
    _Pragma("unroll") \
    for (int j = 0; j < 8; ++j) { \
        const float* g_ = cbase + (size_t)(32 * (k) + q * 8 + j) * CHW; \
        stage256(g_ + p,      &sm.cs[bi][q * 8 + j][0]); \
        stage256(g_ + 64 + p, &sm.cs[bi][q * 8 + j][64]); \
    } \
} while (0)

#define CONSUME(k, bi) do { \
    _Pragma("unroll") \
    for (int cc = 0; cc < 32; ++cc) { \
        float2 xv_ = *(const float2*)&sm.cs[bi][cc][2 * p]; \
        _Pragma("unroll") \
        for (int r = 0; r < 8; ++r) { \
            float wgt_ = WredT[(32 * (k) + cc) * CR + q * 8 + r]; \
            r0[r] = fmaf(wgt_, xv_.x, r0[r]); \
            r1[r] = fmaf(wgt_, xv_.y, r1[r]); \
        } \
    } \
} while (0)

    ISSUE(0, 0); ISSUE(1, 1);     // 32 DMA in flight
    vmcnt_barrier<16>();          // chunk 0 landed (chunk 1 still flying)
    CONSUME(0, 0);
    lgkm_barrier();               // all waves done reading cs[0]
    ISSUE(2, 0);
    vmcnt_barrier<16>();          // chunk 1 landed
    CONSUME(1, 1);
    lgkm_barrier();               // all waves done reading cs[1]
    ISSUE(3, 1);
    vmcnt_barrier<16>();          // chunk 2 landed
    CONSUME(2, 0);
    vm0lgkm_barrier();            // cs[0] free for red2 AND chunk 3 landed
    CONSUME(3, 1);

#pragma unroll
    for (int r = 0; r < 8; ++r)
        *(float2*)&sm.r.red2[q * 8 + r][2 * p] = make_float2(r0[r], r1[r]);

    lgkm_barrier();               // red2 visible to all waves

#undef ISSUE
#undef CONSUME

    // ======== stage 2: kern[18] per pixel for groups {2q,2q+1} ==========
    float k0[18], k1[18];
#pragma unroll
    for (int k = 0; k < 18; ++k) { k0[k] = bkern[18 * q + k]; k1[k] = k0[k]; }
#pragma unroll
    for (int r = 0; r < CR; ++r) {
        float2 rv = *(const float2*)&sm.r.red2[r][2 * p];
#pragma unroll
        for (int k = 0; k < 18; ++k) {
            float wgt = Wkern[(18 * q + k) * CR + r];   // uniform
            k0[k] = fmaf(wgt, rv.x, k0[k]);
            k1[k] = fmaf(wgt, rv.y, k1[k]);
        }
    }

    // ======== stage 3: 32 channels (32q..), taps direct from global =====
    // window cols 2p..2p+3 of rows h..h+2 serve both pixels
    const float* xrow = xb + (size_t)h * WIN + 2 * p;
    float* op = out + (((size_t)(b * C + 32 * q)) * HH + h) * WW + 2 * p;

#pragma unroll
    for (int half = 0; half < 2; ++half) {   // group 2q+half, static kern slice
        float kh0[9], kh1[9];
#pragma unroll
        for (int k = 0; k < 9; ++k) { kh0[k] = k0[9 * half + k]; kh1[k] = k1[9 * half + k]; }

#pragma unroll 2
        for (int cc = 0; cc < 16; ++cc) {
            const float* xp = xrow + (size_t)(32 * q + 16 * half + cc) * CHW;
            float2 ta[3], tb[3];
#pragma unroll
            for (int i = 0; i < 3; ++i) {
                ta[i] = *(const float2*)(xp + i * WIN);       // cols 2p,2p+1
                tb[i] = *(const float2*)(xp + i * WIN + 2);   // cols 2p+2,2p+3
            }
            float a0 = 0.f, a1 = 0.f;
#pragma unroll
            for (int i = 0; i < 3; ++i) {
                a0 = fmaf(kh0[3 * i + 0], ta[i].x, a0);
                a0 = fmaf(kh0[3 * i + 1], ta[i].y, a0);
                a0 = fmaf(kh0[3 * i + 2], tb[i].x, a0);
                a1 = fmaf(kh1[3 * i + 0], ta[i].y, a1);
                a1 = fmaf(kh1[3 * i + 1], tb[i].x, a1);
                a1 = fmaf(kh1[3 * i + 2], tb[i].y, a1);
            }
            *(float2*)(op + (size_t)(16 * half + cc) * HH * WW) = make_float2(a0, a1);
        }
    }
}
} // namespace

extern "C" void kernel_launch(void* const* d_in, const int* in_sizes, int n_in,
                              void* d_out, int out_size, void* d_ws, size_t ws_size,
                              hipStream_t stream) {
    const float* x     = (const float*)d_in[0];
    const float* Wred  = (const float*)d_in[1];
    const float* bred  = (const float*)d_in[2];
    const float* Wkern = (const float*)d_in[3];
    const float* bkern = (const float*)d_in[4];
    float* out   = (float*)d_out;
    float* WredT = (float*)d_ws;   // 16 KB scratch

    transpose_wred<<<16, 256, 0, stream>>>(Wred, WredT);

    // 8 b * 128 h = 1024 blocks, one full output row each
    invol_direct<<<1024, 256, 0, stream>>>(x, WredT, bred, Wkern, bkern, out);
}